// Round 1
// baseline (343.752 us; speedup 1.0000x reference)
//
#include <hip/hip_runtime.h>

// Problem constants (B=2, S=4096, D=512, H=8, Dh=64). f32 I/O, bf16 MFMA inside.
#define MTOT 8192  // B*S

typedef __attribute__((ext_vector_type(8))) short bf16x8;
typedef __attribute__((ext_vector_type(4))) float f32x4;

#if __has_builtin(__builtin_amdgcn_exp2f)
#define EXP2F __builtin_amdgcn_exp2f
#else
#define EXP2F exp2f
#endif

#define SC 0.18033688011112042f  // (1/8) * log2(e), folded into K
#define LDP 72                   // gemm LDS row stride (el): 36 dw == 4 mod 32
#define CTS 136                  // gemm epilogue C-tile stride (el)
#define PST 40                   // attn P row stride (el) for 32-wide j tiles

// Truncation f32->bf16 (1 VALU). Error budget ample (0.031 vs 0.099 thresh).
static __device__ __forceinline__ unsigned short tb(float f) {
  union { float f; unsigned int i; } x;
  x.f = f;
  return (unsigned short)(x.i >> 16);
}
static __device__ __forceinline__ unsigned int pkt(float a, float b) {
  union { float f; unsigned int i; } xa, xb;
  xa.f = a; xb.f = b;
  return (xa.i >> 16) | (xb.i & 0xFFFF0000u);
}
static __device__ __forceinline__ bf16x8 ld8f32_bf16(const float* __restrict__ p) {
  f32x4 lo = *(const f32x4*)p;
  f32x4 hi = *(const f32x4*)(p + 4);
  union { unsigned int u[4]; bf16x8 v; } r;
  r.u[0] = pkt(lo[0], lo[1]);
  r.u[1] = pkt(lo[2], lo[3]);
  r.u[2] = pkt(hi[0], hi[1]);
  r.u[3] = pkt(hi[2], hi[3]);
  return r.v;
}

// ---------------------------------------------------------------------------
// Kernel 1: projection GEMM, LDS-staged (coalesced loads, convert-once).
// Columns: [0,512) Q (Wc,+bc) -> Q_ws[bh][s][dh]
//          [512,1024) V (Wc,+bc) -> Vt_ws[bh][dh][s] (transposed)
//          [1024,1536) K (Wv,+bv, *SC) -> K_ws[bh][s][dh]   (only if nct==12)
// ---------------------------------------------------------------------------
__global__ __launch_bounds__(256) void gemm_qvk(
    const float* __restrict__ mf,
    const float* __restrict__ Wc,
    const float* __restrict__ bc,
    const float* __restrict__ Wv,
    const float* __restrict__ bv,
    unsigned short* __restrict__ ws,
    int nct)
{
  const int bid = blockIdx.x;
  const int tn = bid % nct, tm = bid / nct;
  const int w = threadIdx.x >> 6, lane = threadIdx.x & 63;
  const int n = lane & 15, q = lane >> 4;

  __shared__ alignas(16) unsigned short smem[2 * 128 * LDP];  // As | Bs; Ct overlay
  unsigned short* As = smem;
  unsigned short* Bs = smem + 128 * LDP;

  f32x4 acc[4][4] = {};
  const int rowA0 = tm * 128, colB0 = tn * 128;
  const int sr = threadIdx.x >> 4;          // 0..15 row within round
  const int sc = (threadIdx.x & 15) * 4;    // f32 col offset (16B)

  for (int kc = 0; kc < 512; kc += 64) {
    __syncthreads();
#pragma unroll
    for (int rr = 0; rr < 8; ++rr) {
      const int row = rr * 16 + sr;
      f32x4 av = *(const f32x4*)(mf + (size_t)(rowA0 + row) * 512 + kc + sc);
      uint2 ap; ap.x = pkt(av[0], av[1]); ap.y = pkt(av[2], av[3]);
      *(uint2*)(&As[row * LDP + sc]) = ap;
      const int c = colB0 + row;
      const float* bsrc = (c < 1024) ? (Wc + (size_t)c * 512)
                                     : (Wv + (size_t)(c - 1024) * 512);
      f32x4 bvx = *(const f32x4*)(bsrc + kc + sc);
      uint2 bp; bp.x = pkt(bvx[0], bvx[1]); bp.y = pkt(bvx[2], bvx[3]);
      *(uint2*)(&Bs[row * LDP + sc]) = bp;
    }
    __syncthreads();
#pragma unroll
    for (int ks = 0; ks < 2; ++ks) {
      bf16x8 a[4], b[4];
#pragma unroll
      for (int si = 0; si < 4; ++si)
        a[si] = *(const bf16x8*)(&As[((w >> 1) * 64 + si * 16 + n) * LDP + ks * 32 + q * 8]);
#pragma unroll
      for (int sj = 0; sj < 4; ++sj)
        b[sj] = *(const bf16x8*)(&Bs[((w & 1) * 64 + sj * 16 + n) * LDP + ks * 32 + q * 8]);
#pragma unroll
      for (int si = 0; si < 4; ++si)
#pragma unroll
        for (int sj = 0; sj < 4; ++sj)
          acc[si][sj] = __builtin_amdgcn_mfma_f32_16x16x32_bf16(a[si], b[sj], acc[si][sj], 0, 0, 0);
    }
  }

  // ---- epilogue: LDS transpose (Ct overlays As/Bs) then coalesced stores ----
  __syncthreads();
  unsigned short* Ct = smem;                 // [128][CTS]
  const bool isV = (tn >= 4 && tn < 8);
  const int rl0 = (w >> 1) * 64, cl0 = (w & 1) * 64;

  if (!isV) {
    const bool isK = (tn >= 8);
#pragma unroll
    for (int sj = 0; sj < 4; ++sj) {
      const int c = colB0 + sj * 16 + n;
      const float bias = isK ? bv[c - 1024] : bc[c];
#pragma unroll
      for (int si = 0; si < 4; ++si)
#pragma unroll
        for (int r = 0; r < 4; ++r) {
          float v = acc[si][sj][r] + bias;
          if (isK) v *= SC;
          Ct[(rl0 + si * 16 + q * 4 + r) * CTS + cl0 + sj * 16 + n] = tb(v);
        }
    }
  } else {
#pragma unroll
    for (int sj = 0; sj < 4; ++sj) {
      const float bias = bc[colB0 + sj * 16 + n];
#pragma unroll
      for (int si = 0; si < 4; ++si) {
        uint2 pk;
        pk.x = pkt(acc[si][sj][0] + bias, acc[si][sj][1] + bias);
        pk.y = pkt(acc[si][sj][2] + bias, acc[si][sj][3] + bias);
        *(uint2*)(&Ct[(cl0 + sj * 16 + n) * CTS + rl0 + si * 16 + q * 4]) = pk;
      }
    }
  }
  __syncthreads();

  const int rk = threadIdx.x & 7, rr2 = threadIdx.x >> 3;
#pragma unroll
  for (int rp = 0; rp < 4; ++rp) {
    const int row = rp * 32 + rr2;
#pragma unroll
    for (int ch = 0; ch < 2; ++ch) {
      const int col = ch * 64 + rk * 8;
      bf16x8 v = *(const bf16x8*)(&Ct[row * CTS + col]);
      if (!isV) {
        const int srow = rowA0 + row;
        const int bb = srow >> 12, ss = srow & 4095;
        const int cg = colB0 + col;
        const int cl = (cg >= 1024) ? (cg - 1024) : cg;   // K maps to [0,512)
        const int hh = cl >> 6, dh0 = cl & 63;
        unsigned short* base = (cg >= 1024) ? (ws + (size_t)2 * MTOT * 512) : ws;
        *(bf16x8*)(base + ((size_t)((bb * 8 + hh) * 4096 + ss)) * 64 + dh0) = v;
      } else {
        const int cv = (tn - 4) * 128 + row;              // [0,512)
        const int hh = cv >> 6, dh0 = cv & 63;
        const int sg = rowA0 + col;
        const int bb = sg >> 12, ss = sg & 4095;
        *(bf16x8*)(ws + (size_t)MTOT * 512 +
                   ((size_t)((bb * 8 + hh) * 64 + dh0)) * 4096 + ss) = v;
      }
    }
  }
}

// ---------------------------------------------------------------------------
// Kernel 2: flash attention, occupancy-doubled vs previous version.
//  - 2048 blocks x 2 waves; block = (b,h) x 32 i-rows; waves split j (2048 ea)
//  - per-wave i-tile 32 rows (o = 32 VGPRs), j-tile 32 (bq/bvv 16 VGPRs each)
//    -> peak liveness ~105 regs -> __launch_bounds__(128,4): 4 waves/SIMD,
//       8 blocks/CU resident (16 waves/CU, 50% occupancy cap vs 25% before)
//  - row-sum l computed as scalar exp-sum in registers (replaces ones-MFMA:
//    -4 MFMAs/tile, -20 regs); reduced via 2x shfl_xor at the end
//  - V loads issued at top of iter (QK+exp covers L2 latency); next-iter Q
//    issued after exp (older V drains first, Q stays in flight)
//  - zero in-loop barriers; exact f32 merge of the two j-halves at the end
// ---------------------------------------------------------------------------
template <bool KWS>
__global__ __launch_bounds__(128, 4) void attn_kernel(
    const unsigned short* __restrict__ qvws,
    const float* __restrict__ mf,
    const float* __restrict__ Wv,
    const float* __restrict__ bv,
    float* __restrict__ out)
{
  const int bid = blockIdx.x;
  const int bh = ((bid & 7) << 1) | ((bid >> 3) & 1);  // XCD-local bh pairing
  const int ib = bid >> 4;                             // 0..127
  const int b_ = bh >> 3, h = bh & 7;
  const int w = threadIdx.x >> 6, lane = threadIdx.x & 63;
  const int n = lane & 15, q = lane >> 4;
  const int i0 = ib * 32;

  __shared__ alignas(16) unsigned short PK[2][32 * PST];  // per-wave P tiles
  __shared__ alignas(16) float mO[32 * 68];               // cross-wave o merge
  __shared__ float lbuf[2][32];                           // cross-wave l merge

  const unsigned short* Qb = qvws + (size_t)(bh * 4096) * 64;
  const unsigned short* Vb = qvws + (size_t)MTOT * 512 + (size_t)(bh * 64) * 4096;

  bf16x8 aK[2][2];
  if (KWS) {
    const unsigned short* Kb = qvws + (size_t)2 * MTOT * 512 + (size_t)(bh * 4096) * 64;
#pragma unroll
    for (int sub = 0; sub < 2; ++sub)
#pragma unroll
      for (int s = 0; s < 2; ++s)
        aK[sub][s] = *(const bf16x8*)(Kb + (size_t)(i0 + sub * 16 + n) * 64 + s * 32 + q * 8);
  } else {
    // Fallback: compute K tile (32 rows) in-block; wave w does rows w*16..+16.
    f32x4 ka[4] = {};
    for (int kk = 0; kk < 512; kk += 32) {
      bf16x8 a0 = ld8f32_bf16(mf + (size_t)(b_ * 4096 + i0 + w * 16 + n) * 512 + kk + q * 8);
#pragma unroll
      for (int t = 0; t < 4; ++t) {
        bf16x8 bw = ld8f32_bf16(Wv + (size_t)(h * 64 + t * 16 + n) * 512 + kk + q * 8);
        ka[t] = __builtin_amdgcn_mfma_f32_16x16x32_bf16(a0, bw, ka[t], 0, 0, 0);
      }
    }
    unsigned short* Kt = &PK[0][0];   // borrow PK (2560 el) as [32][72] (2304 el)
#pragma unroll
    for (int t = 0; t < 4; ++t) {
      const float bias = bv[h * 64 + t * 16 + n];
#pragma unroll
      for (int r = 0; r < 4; ++r)
        Kt[(w * 16 + q * 4 + r) * LDP + t * 16 + n] = tb((ka[t][r] + bias) * SC);
    }
    __syncthreads();
#pragma unroll
    for (int sub = 0; sub < 2; ++sub)
#pragma unroll
      for (int s = 0; s < 2; ++s)
        aK[sub][s] = *(const bf16x8*)(&Kt[(sub * 16 + n) * LDP + s * 32 + q * 8]);
    __syncthreads();
  }

  f32x4 o[2][4] = {};
  float lsc[2] = {0.0f, 0.0f};
  unsigned short* Pw = &PK[w][0];
  const int jbase = w * 2048;

  // Prefetch Q for iteration 0.
  bf16x8 bq[2][2], bvv[4];
#pragma unroll
  for (int jt = 0; jt < 2; ++jt)
#pragma unroll
    for (int s = 0; s < 2; ++s)
      bq[jt][s] = *(const bf16x8*)(Qb + (size_t)(jbase + jt * 16 + n) * 64 + s * 32 + q * 8);

  for (int it = 0; it < 64; ++it) {
    const int jc = jbase + it * 32;
    const int j1 = jbase + ((it + 1) & 63) * 32;  // next tile (wraps; redundant last)

    // Issue this-iter V loads first: QK+exp covers their L2 latency, and PV's
    // vmcnt wait on them leaves the (younger) next-iter Q loads in flight.
#pragma unroll
    for (int t = 0; t < 4; ++t)
      bvv[t] = *(const bf16x8*)(Vb + (size_t)(t * 16 + n) * 4096 + jc + q * 8);

    // Scores (transposed: lane holds S[j][i=sub*16+n]); exp; P to per-wave LDS;
    // row-sum accumulated in registers (l[i] lives at lanes with matching n).
#pragma unroll
    for (int sub = 0; sub < 2; ++sub) {
      f32x4 c[2] = {};
#pragma unroll
      for (int jt = 0; jt < 2; ++jt)
#pragma unroll
        for (int s = 0; s < 2; ++s)
          c[jt] = __builtin_amdgcn_mfma_f32_16x16x32_bf16(bq[jt][s], aK[sub][s], c[jt], 0, 0, 0);
#pragma unroll
      for (int jt = 0; jt < 2; ++jt) {
        float e0 = EXP2F(c[jt][0]), e1 = EXP2F(c[jt][1]);
        float e2 = EXP2F(c[jt][2]), e3 = EXP2F(c[jt][3]);
        lsc[sub] += (e0 + e1) + (e2 + e3);
        uint2 pk;
        pk.x = pkt(e0, e1);
        pk.y = pkt(e2, e3);
        *(uint2*)(Pw + (sub * 16 + n) * PST + jt * 16 + q * 4) = pk;
      }
    }

    // Issue next-iter Q (bq regs dead).
#pragma unroll
    for (int jt = 0; jt < 2; ++jt)
#pragma unroll
      for (int s = 0; s < 2; ++s)
        bq[jt][s] = *(const bf16x8*)(Qb + (size_t)(j1 + jt * 16 + n) * 64 + s * 32 + q * 8);

    asm volatile("s_waitcnt lgkmcnt(0)" ::: "memory");  // wave-local P drain

    // P.V (8 MFMAs).
#pragma unroll
    for (int sub = 0; sub < 2; ++sub) {
      bf16x8 pa = *(const bf16x8*)(Pw + (sub * 16 + n) * PST + q * 8);
#pragma unroll
      for (int t = 0; t < 4; ++t)
        o[sub][t] = __builtin_amdgcn_mfma_f32_16x16x32_bf16(pa, bvv[t], o[sub][t], 0, 0, 0);
    }
  }

  // ---- merge the two j-halves (both waves cover the same 32 i-rows) ----
  // l: reduce across the 4 q-groups in-wave, publish per-wave totals.
  float lw[2];
#pragma unroll
  for (int sub = 0; sub < 2; ++sub) {
    float v = lsc[sub];
    v += __shfl_xor(v, 16, 64);
    v += __shfl_xor(v, 32, 64);
    lw[sub] = v;
  }
  // o: wave w exports sub (1-w), keeps sub w; disjoint mO row ranges.
  const int esub = 1 - w, ksub = w;
#pragma unroll
  for (int t = 0; t < 4; ++t)
#pragma unroll
    for (int r = 0; r < 4; ++r)
      mO[(esub * 16 + q * 4 + r) * 68 + t * 16 + n] = o[esub][t][r];
  if (lane < 16) {
    lbuf[w][lane] = lw[0];
    lbuf[w][16 + lane] = lw[1];
  }
  __syncthreads();

  float li[4];
#pragma unroll
  for (int r = 0; r < 4; ++r) {
    const int il = ksub * 16 + q * 4 + r;
    li[r] = 1.0f / (lbuf[0][il] + lbuf[1][il]);
  }
#pragma unroll
  for (int t = 0; t < 4; ++t) {
#pragma unroll
    for (int r = 0; r < 4; ++r) {
      const int i = i0 + ksub * 16 + q * 4 + r;
      const int dh = t * 16 + n;
      const size_t idx = (size_t)(b_ * 4096 + i) * 512 + h * 64 + dh;
      out[idx] = (o[ksub][t][r] + mO[(ksub * 16 + q * 4 + r) * 68 + t * 16 + n]) * li[r]
                 + mf[idx];
    }
  }
}

extern "C" void kernel_launch(void* const* d_in, const int* in_sizes, int n_in,
                              void* d_out, int out_size, void* d_ws, size_t ws_size,
                              hipStream_t stream) {
  const float* mf = (const float*)d_in[0];  // (2,4096,512) f32
  const float* Wc = (const float*)d_in[1];  // (1024,512) f32
  const float* bc = (const float*)d_in[2];  // (1024,) f32
  const float* Wv = (const float*)d_in[3];  // (512,512) f32
  const float* bv = (const float*)d_in[4];  // (512,) f32
  float* out = (float*)d_out;
  unsigned short* ws = (unsigned short*)d_ws;

  // Fast path needs Q(8MB) + V^T(8MB) + K(8MB) in ws.
  const bool kws = ws_size >= (size_t)3 * MTOT * 512 * 2;
  const int nct = kws ? 12 : 8;

  gemm_qvk<<<64 * nct, 256, 0, stream>>>(mf, Wc, bc, Wv, bv, ws, nct);
  if (kws)
    attn_kernel<true><<<2048, 128, 0, stream>>>(ws, mf, Wv, bv, out);
  else
    attn_kernel<false><<<2048, 128, 0, stream>>>(ws, mf, Wv, bv, out);
}

// Round 3
// 239.609 us; speedup vs baseline: 1.4346x; 1.4346x over previous
//
#include <hip/hip_runtime.h>

// Problem constants (B=2, S=4096, D=512, H=8, Dh=64). f32 I/O, bf16 MFMA inside.
#define MTOT 8192  // B*S

typedef __attribute__((ext_vector_type(8))) short bf16x8;
typedef __attribute__((ext_vector_type(4))) float f32x4;

// Native exp2 via builtin ONLY (round-2 lesson: inline-asm v_exp_f32 bypasses
// the compiler's MFMA/trans hazard handling -> silent corruption).
#if __has_builtin(__builtin_amdgcn_exp2f)
#define EXP2F __builtin_amdgcn_exp2f
#else
#define EXP2F exp2f
#endif

#define SC 0.18033688011112042f  // (1/8) * log2(e), folded into K
#define LDP 72                   // LDS row stride (el): 36 dw == 4 mod 32
#define CTS 136                  // epilogue C-tile stride (el)

// Truncation f32->bf16 (1 VALU). Error budget ample (0.031 vs 0.099 thresh).
static __device__ __forceinline__ unsigned short tb(float f) {
  union { float f; unsigned int i; } x;
  x.f = f;
  return (unsigned short)(x.i >> 16);
}
static __device__ __forceinline__ unsigned int pkt(float a, float b) {
  union { float f; unsigned int i; } xa, xb;
  xa.f = a; xb.f = b;
  return (xa.i >> 16) | (xb.i & 0xFFFF0000u);
}
static __device__ __forceinline__ bf16x8 ld8f32_bf16(const float* __restrict__ p) {
  f32x4 lo = *(const f32x4*)p;
  f32x4 hi = *(const f32x4*)(p + 4);
  union { unsigned int u[4]; bf16x8 v; } r;
  r.u[0] = pkt(lo[0], lo[1]);
  r.u[1] = pkt(lo[2], lo[3]);
  r.u[2] = pkt(hi[0], hi[1]);
  r.u[3] = pkt(hi[2], hi[3]);
  return r.v;
}

// ---------------------------------------------------------------------------
// Kernel 1: projection GEMM, LDS-staged (coalesced loads, convert-once).
// Columns: [0,512) Q (Wc,+bc) -> Q_ws[bh][s][dh]
//          [512,1024) V (Wc,+bc) -> Vt_ws[bh][dh][s] (transposed)
//          [1024,1536) K (Wv,+bv, *SC) -> K_ws[bh][s][dh]   (only if nct==12)
// ---------------------------------------------------------------------------
__global__ __launch_bounds__(256) void gemm_qvk(
    const float* __restrict__ mf,
    const float* __restrict__ Wc,
    const float* __restrict__ bc,
    const float* __restrict__ Wv,
    const float* __restrict__ bv,
    unsigned short* __restrict__ ws,
    int nct)
{
  const int bid = blockIdx.x;
  const int tn = bid % nct, tm = bid / nct;
  const int w = threadIdx.x >> 6, lane = threadIdx.x & 63;
  const int n = lane & 15, q = lane >> 4;

  __shared__ alignas(16) unsigned short smem[2 * 128 * LDP];  // As | Bs; Ct overlay
  unsigned short* As = smem;
  unsigned short* Bs = smem + 128 * LDP;

  f32x4 acc[4][4] = {};
  const int rowA0 = tm * 128, colB0 = tn * 128;
  const int sr = threadIdx.x >> 4;          // 0..15 row within round
  const int sc = (threadIdx.x & 15) * 4;    // f32 col offset (16B)

  for (int kc = 0; kc < 512; kc += 64) {
    __syncthreads();
#pragma unroll
    for (int rr = 0; rr < 8; ++rr) {
      const int row = rr * 16 + sr;
      f32x4 av = *(const f32x4*)(mf + (size_t)(rowA0 + row) * 512 + kc + sc);
      uint2 ap; ap.x = pkt(av[0], av[1]); ap.y = pkt(av[2], av[3]);
      *(uint2*)(&As[row * LDP + sc]) = ap;
      const int c = colB0 + row;
      const float* bsrc = (c < 1024) ? (Wc + (size_t)c * 512)
                                     : (Wv + (size_t)(c - 1024) * 512);
      f32x4 bvx = *(const f32x4*)(bsrc + kc + sc);
      uint2 bp; bp.x = pkt(bvx[0], bvx[1]); bp.y = pkt(bvx[2], bvx[3]);
      *(uint2*)(&Bs[row * LDP + sc]) = bp;
    }
    __syncthreads();
#pragma unroll
    for (int ks = 0; ks < 2; ++ks) {
      bf16x8 a[4], b[4];
#pragma unroll
      for (int si = 0; si < 4; ++si)
        a[si] = *(const bf16x8*)(&As[((w >> 1) * 64 + si * 16 + n) * LDP + ks * 32 + q * 8]);
#pragma unroll
      for (int sj = 0; sj < 4; ++sj)
        b[sj] = *(const bf16x8*)(&Bs[((w & 1) * 64 + sj * 16 + n) * LDP + ks * 32 + q * 8]);
#pragma unroll
      for (int si = 0; si < 4; ++si)
#pragma unroll
        for (int sj = 0; sj < 4; ++sj)
          acc[si][sj] = __builtin_amdgcn_mfma_f32_16x16x32_bf16(a[si], b[sj], acc[si][sj], 0, 0, 0);
    }
  }

  // ---- epilogue: LDS transpose (Ct overlays As/Bs) then coalesced stores ----
  __syncthreads();
  unsigned short* Ct = smem;                 // [128][CTS]
  const bool isV = (tn >= 4 && tn < 8);
  const int rl0 = (w >> 1) * 64, cl0 = (w & 1) * 64;

  if (!isV) {
    const bool isK = (tn >= 8);
#pragma unroll
    for (int sj = 0; sj < 4; ++sj) {
      const int c = colB0 + sj * 16 + n;
      const float bias = isK ? bv[c - 1024] : bc[c];
#pragma unroll
      for (int si = 0; si < 4; ++si)
#pragma unroll
        for (int r = 0; r < 4; ++r) {
          float v = acc[si][sj][r] + bias;
          if (isK) v *= SC;
          Ct[(rl0 + si * 16 + q * 4 + r) * CTS + cl0 + sj * 16 + n] = tb(v);
        }
    }
  } else {
#pragma unroll
    for (int sj = 0; sj < 4; ++sj) {
      const float bias = bc[colB0 + sj * 16 + n];
#pragma unroll
      for (int si = 0; si < 4; ++si) {
        uint2 pk;
        pk.x = pkt(acc[si][sj][0] + bias, acc[si][sj][1] + bias);
        pk.y = pkt(acc[si][sj][2] + bias, acc[si][sj][3] + bias);
        *(uint2*)(&Ct[(cl0 + sj * 16 + n) * CTS + rl0 + si * 16 + q * 4]) = pk;
      }
    }
  }
  __syncthreads();

  const int rk = threadIdx.x & 7, rr2 = threadIdx.x >> 3;
#pragma unroll
  for (int rp = 0; rp < 4; ++rp) {
    const int row = rp * 32 + rr2;
#pragma unroll
    for (int ch = 0; ch < 2; ++ch) {
      const int col = ch * 64 + rk * 8;
      bf16x8 v = *(const bf16x8*)(&Ct[row * CTS + col]);
      if (!isV) {
        const int srow = rowA0 + row;
        const int bb = srow >> 12, ss = srow & 4095;
        const int cg = colB0 + col;
        const int cl = (cg >= 1024) ? (cg - 1024) : cg;   // K maps to [0,512)
        const int hh = cl >> 6, dh0 = cl & 63;
        unsigned short* base = (cg >= 1024) ? (ws + (size_t)2 * MTOT * 512) : ws;
        *(bf16x8*)(base + ((size_t)((bb * 8 + hh) * 4096 + ss)) * 64 + dh0) = v;
      } else {
        const int cv = (tn - 4) * 128 + row;              // [0,512)
        const int hh = cv >> 6, dh0 = cv & 63;
        const int sg = rowA0 + col;
        const int bb = sg >> 12, ss = sg & 4095;
        *(bf16x8*)(ws + (size_t)MTOT * 512 +
                   ((size_t)((bb * 8 + hh) * 64 + dh0)) * 4096 + ss) = v;
      }
    }
  }
}

// ---------------------------------------------------------------------------
// Kernel 2: flash attention, per-sub software pipeline, zero in-loop barriers.
//  - block = 2 waves, one (b,h) x 64 i-rows; waves split j (exact f32 merge)
//  - XCD swizzle: XCD x gets bh {2x,2x+1} -> Q/V/K working set L2-resident
//  - row-sum via scalar f32 exp-sum (round-1-proven), NOT ones-MFMA:
//    -8 MFMA/iter and ~20 fewer live registers (spill fix: round-0 showed
//    86MB of scratch WRITE_SIZE = ~5 dwords spilled per iter)
//  - per-sub pipeline: QK(sub+1) MFMAs issue BEFORE exp(sub), so trans-pipe
//    exps and the per-sub lgkm waits overlap MFMA execution
// ---------------------------------------------------------------------------
template <bool KWS>
__global__ __launch_bounds__(128, 2) void attn_kernel(
    const unsigned short* __restrict__ qvws,
    const float* __restrict__ mf,
    const float* __restrict__ Wv,
    const float* __restrict__ bv,
    float* __restrict__ out)
{
  const int bid = blockIdx.x;
  const int bh = ((bid & 7) << 1) | ((bid >> 3) & 1);  // XCD-local bh pairing
  const int ib = bid >> 4;
  const int b_ = bh >> 3, h = bh & 7;
  const int w = threadIdx.x >> 6, lane = threadIdx.x & 63;
  const int n = lane & 15, q = lane >> 4;
  const int i0 = ib * 64;

  __shared__ alignas(16) unsigned short PK[2][64 * LDP];
  __shared__ float lbuf[2][64];

  const unsigned short* Qb = qvws + (size_t)(bh * 4096) * 64;
  const unsigned short* Vb = qvws + (size_t)MTOT * 512 + (size_t)(bh * 64) * 4096;

  bf16x8 aK[4][2];
  if (KWS) {
    const unsigned short* Kb = qvws + (size_t)2 * MTOT * 512 + (size_t)(bh * 4096) * 64;
#pragma unroll
    for (int sub = 0; sub < 4; ++sub)
#pragma unroll
      for (int s = 0; s < 2; ++s)
        aK[sub][s] = *(const bf16x8*)(Kb + (size_t)(i0 + sub * 16 + n) * 64 + s * 32 + q * 8);
  } else {
    // Fallback: compute K tile (64 rows) in-block; wave w does subs {2w,2w+1}.
    f32x4 ka[2][4] = {};
    for (int kk = 0; kk < 512; kk += 32) {
      bf16x8 a0 = ld8f32_bf16(mf + (size_t)(b_ * 4096 + i0 + (2 * w + 0) * 16 + n) * 512 + kk + q * 8);
      bf16x8 a1 = ld8f32_bf16(mf + (size_t)(b_ * 4096 + i0 + (2 * w + 1) * 16 + n) * 512 + kk + q * 8);
#pragma unroll
      for (int t = 0; t < 4; ++t) {
        bf16x8 bw = ld8f32_bf16(Wv + (size_t)(h * 64 + t * 16 + n) * 512 + kk + q * 8);
        ka[0][t] = __builtin_amdgcn_mfma_f32_16x16x32_bf16(a0, bw, ka[0][t], 0, 0, 0);
        ka[1][t] = __builtin_amdgcn_mfma_f32_16x16x32_bf16(a1, bw, ka[1][t], 0, 0, 0);
      }
    }
#pragma unroll
    for (int sl = 0; sl < 2; ++sl)
#pragma unroll
      for (int t = 0; t < 4; ++t) {
        const float bias = bv[h * 64 + t * 16 + n];
#pragma unroll
        for (int r = 0; r < 4; ++r)
          PK[0][((2 * w + sl) * 16 + q * 4 + r) * LDP + t * 16 + n] =
              tb((ka[sl][t][r] + bias) * SC);
      }
    __syncthreads();
#pragma unroll
    for (int sub = 0; sub < 4; ++sub)
#pragma unroll
      for (int s = 0; s < 2; ++s)
        aK[sub][s] = *(const bf16x8*)(&PK[0][(sub * 16 + n) * LDP + s * 32 + q * 8]);
    __syncthreads();
  }

  f32x4 o[4][4] = {};
  float lsc[4] = {0.0f, 0.0f, 0.0f, 0.0f};
  unsigned short* Pw = &PK[w][0];
  const int jbase = w * 2048;

  // Prefetch iteration 0.
  bf16x8 bq[4][2], bvv[4][2];
#pragma unroll
  for (int jt = 0; jt < 4; ++jt)
#pragma unroll
    for (int s = 0; s < 2; ++s)
      bq[jt][s] = *(const bf16x8*)(Qb + (size_t)(jbase + jt * 16 + n) * 64 + s * 32 + q * 8);
#pragma unroll
  for (int t = 0; t < 4; ++t)
#pragma unroll
    for (int s = 0; s < 2; ++s)
      bvv[t][s] = *(const bf16x8*)(Vb + (size_t)(t * 16 + n) * 4096 + jbase + s * 32 + q * 8);

  for (int it = 0; it < 32; ++it) {
    const int j1 = jbase + ((it + 1) & 31) * 64;  // next tile (wraps; redundant last)

    // Transposed scores: lane holds S[j = jt*16+q*4+r][i = sub*16+n].
    f32x4 c[4][4];
    // QK(0) first; QK(sub+1) then issues ahead of exp(sub) in the rotation.
#pragma unroll
    for (int jt = 0; jt < 4; ++jt) {
      f32x4 z = {};
      z = __builtin_amdgcn_mfma_f32_16x16x32_bf16(bq[jt][0], aK[0][0], z, 0, 0, 0);
      z = __builtin_amdgcn_mfma_f32_16x16x32_bf16(bq[jt][1], aK[0][1], z, 0, 0, 0);
      c[0][jt] = z;
    }

#pragma unroll
    for (int sub = 0; sub < 4; ++sub) {
      if (sub < 3) {
#pragma unroll
        for (int jt = 0; jt < 4; ++jt) {
          f32x4 z = {};
          z = __builtin_amdgcn_mfma_f32_16x16x32_bf16(bq[jt][0], aK[sub + 1][0], z, 0, 0, 0);
          z = __builtin_amdgcn_mfma_f32_16x16x32_bf16(bq[jt][1], aK[sub + 1][1], z, 0, 0, 0);
          c[sub + 1][jt] = z;
        }
      }
      if (sub == 2) {
        // bq regs dead after QK(3) issue -- prefetch next-iter Q now.
#pragma unroll
        for (int jt = 0; jt < 4; ++jt)
#pragma unroll
          for (int s = 0; s < 2; ++s)
            bq[jt][s] = *(const bf16x8*)(Qb + (size_t)(j1 + jt * 16 + n) * 64 + s * 32 + q * 8);
      }

      // exp + pack + store P(sub); scalar row-sum partials in registers.
#pragma unroll
      for (int jt = 0; jt < 4; ++jt) {
        float e0 = EXP2F(c[sub][jt][0]), e1 = EXP2F(c[sub][jt][1]);
        float e2 = EXP2F(c[sub][jt][2]), e3 = EXP2F(c[sub][jt][3]);
        lsc[sub] += (e0 + e1) + (e2 + e3);
        uint2 pk;
        pk.x = pkt(e0, e1);
        pk.y = pkt(e2, e3);
        *(uint2*)(Pw + (sub * 16 + n) * LDP + jt * 16 + q * 4) = pk;
      }

      asm volatile("s_waitcnt lgkmcnt(0)" ::: "memory");  // drain P(sub) stores

      // PV(sub): 8 MFMAs; P(sub) rows are exactly the rows written above.
#pragma unroll
      for (int s = 0; s < 2; ++s) {
        bf16x8 pa = *(const bf16x8*)(Pw + (sub * 16 + n) * LDP + s * 32 + q * 8);
#pragma unroll
        for (int t = 0; t < 4; ++t)
          o[sub][t] = __builtin_amdgcn_mfma_f32_16x16x32_bf16(pa, bvv[t][s], o[sub][t], 0, 0, 0);
      }
    }

    // Issue next-iter bvv (bvv regs dead after PV(3)).
#pragma unroll
    for (int t = 0; t < 4; ++t)
#pragma unroll
      for (int s = 0; s < 2; ++s)
        bvv[t][s] = *(const bf16x8*)(Vb + (size_t)(t * 16 + n) * 4096 + j1 + s * 32 + q * 8);
  }

  // ---- merge: row-sums via shfl + LDS; o via LDS exchange (exact f32) ----
  float lw[4];
#pragma unroll
  for (int sub = 0; sub < 4; ++sub) {
    float v = lsc[sub];
    v += __shfl_xor(v, 16, 64);
    v += __shfl_xor(v, 32, 64);
    lw[sub] = v;   // total over this wave's j-half, for i = sub*16 + n
  }

  __syncthreads();                    // both waves done with P regions
  float* mO = (float*)&PK[0][0];      // 64 x (stride 68) f32, overlays P
  const int ebase = (w == 0) ? 0 : 32;      // where I write
  const int rbase = (w == 0) ? 32 : 0;      // where I read
  const int esub0 = (w == 0) ? 2 : 0;       // subs I export
  const int ksub0 = (w == 0) ? 0 : 2;       // subs I keep
#pragma unroll
  for (int sl = 0; sl < 2; ++sl) {
    const int sub = esub0 + sl;
#pragma unroll
    for (int t = 0; t < 4; ++t)
#pragma unroll
      for (int r = 0; r < 4; ++r)
        mO[(ebase + sl * 16 + q * 4 + r) * 68 + t * 16 + n] = o[sub][t][r];
  }
  if (lane < 16) {
#pragma unroll
    for (int sub = 0; sub < 4; ++sub)
      lbuf[w][sub * 16 + lane] = lw[sub];
  }
  __syncthreads();
#pragma unroll
  for (int sl = 0; sl < 2; ++sl) {
    const int sub = ksub0 + sl;
    float li[4];
#pragma unroll
    for (int r = 0; r < 4; ++r) {
      const int il = sub * 16 + q * 4 + r;
      li[r] = 1.0f / (lbuf[0][il] + lbuf[1][il]);
    }
#pragma unroll
    for (int t = 0; t < 4; ++t) {
#pragma unroll
      for (int r = 0; r < 4; ++r) {
        const int i = i0 + sub * 16 + q * 4 + r;
        const int dh = t * 16 + n;
        const size_t idx = (size_t)(b_ * 4096 + i) * 512 + h * 64 + dh;
        out[idx] = (o[sub][t][r] + mO[(rbase + sl * 16 + q * 4 + r) * 68 + t * 16 + n]) * li[r]
                   + mf[idx];
      }
    }
  }
}

extern "C" void kernel_launch(void* const* d_in, const int* in_sizes, int n_in,
                              void* d_out, int out_size, void* d_ws, size_t ws_size,
                              hipStream_t stream) {
  const float* mf = (const float*)d_in[0];  // (2,4096,512) f32
  const float* Wc = (const float*)d_in[1];  // (1024,512) f32
  const float* bc = (const float*)d_in[2];  // (1024,) f32
  const float* Wv = (const float*)d_in[3];  // (512,512) f32
  const float* bv = (const float*)d_in[4];  // (512,) f32
  float* out = (float*)d_out;
  unsigned short* ws = (unsigned short*)d_ws;

  // Fast path needs Q(8MB) + V^T(8MB) + K(8MB) in ws.
  const bool kws = ws_size >= (size_t)3 * MTOT * 512 * 2;
  const int nct = kws ? 12 : 8;

  gemm_qvk<<<64 * nct, 256, 0, stream>>>(mf, Wc, bc, Wv, bv, ws, nct);
  if (kws)
    attn_kernel<true><<<1024, 128, 0, stream>>>(ws, mf, Wv, bv, out);
  else
    attn_kernel<false><<<1024, 128, 0, stream>>>(ws, mf, Wv, bv, out);
}